// Round 1
// baseline (1154.292 us; speedup 1.0000x reference)
//
#include <hip/hip_runtime.h>
#include <hip/hip_bf16.h>

typedef short short8v __attribute__((ext_vector_type(8)));
typedef short short4v __attribute__((ext_vector_type(4)));
typedef float f32x4v __attribute__((ext_vector_type(4)));

#define T_LEN 512
#define BATCH 64
#define INDIM 1280
#define HDIM 128
#define G4 512      // 4*H (one direction)
#define NCOLS 1024  // both directions
#define NCLS 263

typedef __attribute__((address_space(1))) const void gvoid_t;
typedef __attribute__((address_space(3))) void lvoid_t;
#define GLOAD_LDS16(g, l) __builtin_amdgcn_global_load_lds((gvoid_t*)(g), (lvoid_t*)(l), 16, 0, 0)

static __device__ __forceinline__ short f2bf(float f) {
    union { float f; unsigned u; } v; v.f = f;
    unsigned r = v.u + 0x7FFF + ((v.u >> 16) & 1);
    return (short)(r >> 16);
}

// ---------------- convert x (fp32) -> bf16 ----------------
__global__ void convert_x_kernel(const float4* __restrict__ x, short4v* __restrict__ out, int n4) {
    int i = blockIdx.x * blockDim.x + threadIdx.x;
    int stride = gridDim.x * blockDim.x;
    for (; i < n4; i += stride) {
        float4 v = x[i];
        short4v o;
        o[0] = f2bf(v.x); o[1] = f2bf(v.y); o[2] = f2bf(v.z); o[3] = f2bf(v.w);
        out[i] = o;
    }
}

// ---------------- convert Wih_f/Wih_b -> bf16 [1024][1280], combine biases ----------------
__global__ void convert_w_kernel(const float* __restrict__ Wf, const float* __restrict__ Wb,
                                 const float* __restrict__ bihf, const float* __restrict__ bhhf,
                                 const float* __restrict__ bihb, const float* __restrict__ bhhb,
                                 short* __restrict__ wout, float* __restrict__ biasc) {
    int i = blockIdx.x * blockDim.x + threadIdx.x;
    int stride = gridDim.x * blockDim.x;
    const int n4 = (G4 * INDIM) / 4;  // 163840 float4 per direction
    for (int k = i; k < 2 * n4; k += stride) {
        const float4* src = (k < n4) ? (const float4*)Wf : (const float4*)Wb;
        float4 v = src[(k < n4) ? k : (k - n4)];
        short4v o;
        o[0] = f2bf(v.x); o[1] = f2bf(v.y); o[2] = f2bf(v.z); o[3] = f2bf(v.w);
        ((short4v*)wout)[k] = o;
    }
    if (i < NCOLS)
        biasc[i] = (i < G4) ? (bihf[i] + bhhf[i]) : (bihb[i - G4] + bhhb[i - G4]);
}

// ---------------- big GEMM: xp[M=32768][1024] = x_bf16[M][1280] * w_bf16[1024][1280]^T + bias ----------------
#define BM 128
#define BN 128
#define BK 32

__global__ __launch_bounds__(256) void gemm_xp_kernel(const short* __restrict__ A,
                                                      const short* __restrict__ Bw,
                                                      const float* __restrict__ bias,
                                                      float* __restrict__ C) {
    __shared__ __align__(16) short As[BM * BK];
    __shared__ __align__(16) short Bs[BN * BK];
    const int tid = threadIdx.x;
    const int w = tid >> 6;
    const int l = tid & 63;
    const int bm = blockIdx.x * BM;
    const int bn = blockIdx.y * BN;
    const int wm = (w >> 1) * 64;
    const int wn = (w & 1) * 64;
    const int lr = l & 15;
    const int lk = (l >> 4) * 8;

    f32x4v acc[4][4];
#pragma unroll
    for (int m = 0; m < 4; m++)
#pragma unroll
        for (int n = 0; n < 4; n++) acc[m][n] = (f32x4v)0.0f;

    const int srow = tid >> 2;        // 0..63
    const int scol = (tid & 3) * 8;   // bf16 k-offset

    // prologue: stage tile k0=0
#pragma unroll
    for (int i = 0; i < 2; i++) {
        GLOAD_LDS16(A + (long)(bm + i * 64 + srow) * INDIM + scol, &As[(i * 64 + (w << 4)) * BK]);
        GLOAD_LDS16(Bw + (long)(bn + i * 64 + srow) * INDIM + scol, &Bs[(i * 64 + (w << 4)) * BK]);
    }

    for (int k0 = 0; k0 < INDIM; k0 += BK) {
        __syncthreads();  // staged data visible
        short8v af[4], bf[4];
#pragma unroll
        for (int m = 0; m < 4; m++) af[m] = *(const short8v*)&As[(wm + m * 16 + lr) * BK + lk];
#pragma unroll
        for (int n = 0; n < 4; n++) bf[n] = *(const short8v*)&Bs[(wn + n * 16 + lr) * BK + lk];
        __syncthreads();  // all waves done reading LDS
        if (k0 + BK < INDIM) {
            const int k1 = k0 + BK;
#pragma unroll
            for (int i = 0; i < 2; i++) {
                GLOAD_LDS16(A + (long)(bm + i * 64 + srow) * INDIM + k1 + scol, &As[(i * 64 + (w << 4)) * BK]);
                GLOAD_LDS16(Bw + (long)(bn + i * 64 + srow) * INDIM + k1 + scol, &Bs[(i * 64 + (w << 4)) * BK]);
            }
        }
#pragma unroll
        for (int m = 0; m < 4; m++)
#pragma unroll
            for (int n = 0; n < 4; n++)
                acc[m][n] = __builtin_amdgcn_mfma_f32_16x16x32_bf16(af[m], bf[n], acc[m][n], 0, 0, 0);
    }

    // epilogue: add bias, store fp32
#pragma unroll
    for (int m = 0; m < 4; m++) {
        const int row = bm + wm + m * 16 + (l >> 4) * 4;
#pragma unroll
        for (int n = 0; n < 4; n++) {
            const int col = bn + wn + n * 16 + lr;
            const float bv = bias[col];
#pragma unroll
            for (int r = 0; r < 4; r++)
                C[(long)(row + r) * NCOLS + col] = acc[m][n][r] + bv;
        }
    }
}

// ---------------- recurrence: 8 blocks = 4 batch-groups x 2 directions ----------------
__global__ __launch_bounds__(512, 2) void lstm_rec_kernel(const float* __restrict__ xp,
                                                          const float* __restrict__ Whh_f,
                                                          const float* __restrict__ Whh_b,
                                                          float* __restrict__ pooled) {
    __shared__ __align__(16) float gates[G4 * 21];   // col-major [gatecol][batch], stride 21
    __shared__ __align__(16) short hbf[16 * 136];    // h in bf16, row stride 136

    const int bid = blockIdx.x;  // 0..7
    const int d = bid & 1;
    const int b0 = (bid >> 1) * 16;
    const int tid = threadIdx.x;
    const int w = tid >> 6;
    const int l = tid & 63;
    const int lr = l & 15;
    const int lg = l >> 4;       // 0..3
    const int lk = lg * 8;

    const float* __restrict__ Whh = d ? Whh_b : Whh_f;

    // preload Whh fragments (time-invariant): wave w owns gate cols [64w, 64w+64)
    short8v bfrag[4][4];
#pragma unroll
    for (int nt = 0; nt < 4; nt++) {
        const int gc = w * 64 + nt * 16 + lr;
#pragma unroll
        for (int kk = 0; kk < 4; kk++) {
            const float* src = Whh + gc * HDIM + kk * 32 + lk;
            short8v f;
#pragma unroll
            for (int j = 0; j < 8; j++) f[j] = f2bf(src[j]);
            bfrag[nt][kk] = f;
        }
    }

    // zero h
    for (int i = tid; i < 16 * 136; i += 512) hbf[i] = 0;

    const int eb = tid >> 5;  // batch row 0..15 (elementwise ownership)
    const int ej = tid & 31;  // base gate-elem
    float c[4] = {0.f, 0.f, 0.f, 0.f};
    float hmax[4] = {-1e30f, -1e30f, -1e30f, -1e30f};

    __syncthreads();

    for (int t = 0; t < T_LEN; t++) {
        const int tt = d ? (T_LEN - 1 - t) : t;

        // issue xp loads for this step (consumed in phase B, after the mid barrier)
        float xv[4][4];
        {
            const float* xrow = xp + ((long)(b0 + eb) * T_LEN + tt) * NCOLS + d * G4;
#pragma unroll
            for (int q = 0; q < 4; q++)
#pragma unroll
                for (int p = 0; p < 4; p++) xv[q][p] = xrow[q * 128 + ej + 32 * p];
        }

        // phase A: gates_mm = h @ Whh^T via MFMA
        short8v af[4];
#pragma unroll
        for (int kk = 0; kk < 4; kk++)
            af[kk] = *(const short8v*)&hbf[lr * 136 + kk * 32 + lk];
#pragma unroll
        for (int nt = 0; nt < 4; nt++) {
            f32x4v a = (f32x4v)0.0f;
#pragma unroll
            for (int kk = 0; kk < 4; kk++)
                a = __builtin_amdgcn_mfma_f32_16x16x32_bf16(af[kk], bfrag[nt][kk], a, 0, 0, 0);
            const int gc = w * 64 + nt * 16 + lr;
#pragma unroll
            for (int r = 0; r < 4; r++) gates[gc * 21 + lg * 4 + r] = a[r];
        }
        __syncthreads();

        // phase B: gate nonlinearities + state update
#pragma unroll
        for (int p = 0; p < 4; p++) {
            const int j = ej + 32 * p;
            float gi = gates[(j)*21 + eb] + xv[0][p];
            float gf = gates[(128 + j) * 21 + eb] + xv[1][p];
            float gg = gates[(256 + j) * 21 + eb] + xv[2][p];
            float go = gates[(384 + j) * 21 + eb] + xv[3][p];
            float si = 1.0f / (1.0f + __expf(-gi));
            float sf = 1.0f / (1.0f + __expf(-gf));
            float tg = 1.0f - 2.0f / (1.0f + __expf(2.0f * gg));
            float so = 1.0f / (1.0f + __expf(-go));
            c[p] = sf * c[p] + si * tg;
            float tc = 1.0f - 2.0f / (1.0f + __expf(2.0f * c[p]));
            float h = so * tc;
            hmax[p] = fmaxf(hmax[p], h);
            hbf[eb * 136 + j] = f2bf(h);
        }
        __syncthreads();
    }

#pragma unroll
    for (int p = 0; p < 4; p++)
        pooled[(b0 + eb) * 256 + d * 128 + ej + 32 * p] = hmax[p];
}

// ---------------- head: out[64][263] = pooled[64][256] @ W1^T + b1 ----------------
__global__ void logits_kernel(const float* __restrict__ pooled, const float* __restrict__ W1,
                              const float* __restrict__ b1, float* __restrict__ out) {
    __shared__ float p[256];
    const int b = blockIdx.x;
    const int n = threadIdx.x;
    if (n < 256) p[n] = pooled[b * 256 + n];
    __syncthreads();
    if (n < NCLS) {
        float s = b1[n];
        const float* wr = W1 + n * 256;
#pragma unroll 8
        for (int k = 0; k < 256; k++) s += p[k] * wr[k];
        out[b * NCLS + n] = s;
    }
}

extern "C" void kernel_launch(void* const* d_in, const int* in_sizes, int n_in,
                              void* d_out, int out_size, void* d_ws, size_t ws_size,
                              hipStream_t stream) {
    (void)in_sizes; (void)n_in; (void)out_size; (void)ws_size;
    const float* x     = (const float*)d_in[0];
    const float* Wih_f = (const float*)d_in[1];
    const float* Whh_f = (const float*)d_in[2];
    const float* bih_f = (const float*)d_in[3];
    const float* bhh_f = (const float*)d_in[4];
    const float* Wih_b = (const float*)d_in[5];
    const float* Whh_b = (const float*)d_in[6];
    const float* bih_b = (const float*)d_in[7];
    const float* bhh_b = (const float*)d_in[8];
    const float* W1    = (const float*)d_in[9];
    const float* b1    = (const float*)d_in[10];
    float* out = (float*)d_out;

    char* ws = (char*)d_ws;
    short* x_bf   = (short*)ws;                    // 32768*1280*2  = 83,886,080
    short* w_bf   = (short*)(ws + 83886080);       // 1024*1280*2   =  2,621,440
    float* biasc  = (float*)(ws + 86507520);       // 1024*4        =      4,096
    float* xp     = (float*)(ws + 86511616);       // 32768*1024*4  = 134,217,728
    float* pooled = (float*)(ws + 220729344);      // 64*256*4      =     65,536

    convert_x_kernel<<<2048, 256, 0, stream>>>((const float4*)x, (short4v*)x_bf, (T_LEN * BATCH * INDIM) / 4);
    convert_w_kernel<<<512, 256, 0, stream>>>(Wih_f, Wih_b, bih_f, bhh_f, bih_b, bhh_b, w_bf, biasc);
    dim3 g(BATCH * T_LEN / BM, NCOLS / BN);  // (256, 8)
    gemm_xp_kernel<<<g, 256, 0, stream>>>(x_bf, w_bf, biasc, xp);
    lstm_rec_kernel<<<8, 512, 0, stream>>>(xp, Whh_f, Whh_b, pooled);
    logits_kernel<<<64, 320, 0, stream>>>(pooled, W1, b1, out);
}

// Round 2
// 939.120 us; speedup vs baseline: 1.2291x; 1.2291x over previous
//
#include <hip/hip_runtime.h>
#include <hip/hip_bf16.h>

typedef short short8v __attribute__((ext_vector_type(8)));
typedef short short4v __attribute__((ext_vector_type(4)));
typedef float f32x4v __attribute__((ext_vector_type(4)));

#define T_LEN 512
#define BATCH 64
#define INDIM 1280
#define HDIM 128
#define G4 512      // 4*H (one direction)
#define NCOLS 1024  // both directions
#define NCLS 263

typedef __attribute__((address_space(1))) const void gvoid_t;
typedef __attribute__((address_space(3))) void lvoid_t;
#define GLOAD_LDS16(g, l) __builtin_amdgcn_global_load_lds((gvoid_t*)(g), (lvoid_t*)(l), 16, 0, 0)

static __device__ __forceinline__ short f2bf(float f) {
    union { float f; unsigned u; } v; v.f = f;
    unsigned r = v.u + 0x7FFF + ((v.u >> 16) & 1);
    return (short)(r >> 16);
}

// ---------------- convert x (fp32) -> bf16 ----------------
__global__ void convert_x_kernel(const float4* __restrict__ x, short4v* __restrict__ out, int n4) {
    int i = blockIdx.x * blockDim.x + threadIdx.x;
    int stride = gridDim.x * blockDim.x;
    for (; i < n4; i += stride) {
        float4 v = x[i];
        short4v o;
        o[0] = f2bf(v.x); o[1] = f2bf(v.y); o[2] = f2bf(v.z); o[3] = f2bf(v.w);
        out[i] = o;
    }
}

// ---------------- convert Wih_f/Wih_b -> bf16 [1024][1280], combine biases ----------------
__global__ void convert_w_kernel(const float* __restrict__ Wf, const float* __restrict__ Wb,
                                 const float* __restrict__ bihf, const float* __restrict__ bhhf,
                                 const float* __restrict__ bihb, const float* __restrict__ bhhb,
                                 short* __restrict__ wout, float* __restrict__ biasc) {
    int i = blockIdx.x * blockDim.x + threadIdx.x;
    int stride = gridDim.x * blockDim.x;
    const int n4 = (G4 * INDIM) / 4;  // 163840 float4 per direction
    for (int k = i; k < 2 * n4; k += stride) {
        const float4* src = (k < n4) ? (const float4*)Wf : (const float4*)Wb;
        float4 v = src[(k < n4) ? k : (k - n4)];
        short4v o;
        o[0] = f2bf(v.x); o[1] = f2bf(v.y); o[2] = f2bf(v.z); o[3] = f2bf(v.w);
        ((short4v*)wout)[k] = o;
    }
    if (i < NCOLS)
        biasc[i] = (i < G4) ? (bihf[i] + bhhf[i]) : (bihb[i - G4] + bhhb[i - G4]);
}

// ---------------- big GEMM: xp[M=32768][1024] = x_bf16[M][1280] * w_bf16[1024][1280]^T + bias ----------------
#define BM 128
#define BN 128
#define BK 32

__global__ __launch_bounds__(256) void gemm_xp_kernel(const short* __restrict__ A,
                                                      const short* __restrict__ Bw,
                                                      const float* __restrict__ bias,
                                                      float* __restrict__ C) {
    __shared__ __align__(16) short As[BM * BK];
    __shared__ __align__(16) short Bs[BN * BK];
    const int tid = threadIdx.x;
    const int w = tid >> 6;
    const int l = tid & 63;
    const int bm = blockIdx.x * BM;
    const int bn = blockIdx.y * BN;
    const int wm = (w >> 1) * 64;
    const int wn = (w & 1) * 64;
    const int lr = l & 15;
    const int lk = (l >> 4) * 8;

    f32x4v acc[4][4];
#pragma unroll
    for (int m = 0; m < 4; m++)
#pragma unroll
        for (int n = 0; n < 4; n++) acc[m][n] = (f32x4v)0.0f;

    const int srow = tid >> 2;        // 0..63
    const int scol = (tid & 3) * 8;   // bf16 k-offset

    // prologue: stage tile k0=0
#pragma unroll
    for (int i = 0; i < 2; i++) {
        GLOAD_LDS16(A + (long)(bm + i * 64 + srow) * INDIM + scol, &As[(i * 64 + (w << 4)) * BK]);
        GLOAD_LDS16(Bw + (long)(bn + i * 64 + srow) * INDIM + scol, &Bs[(i * 64 + (w << 4)) * BK]);
    }

    for (int k0 = 0; k0 < INDIM; k0 += BK) {
        __syncthreads();  // staged data visible
        short8v af[4], bf[4];
#pragma unroll
        for (int m = 0; m < 4; m++) af[m] = *(const short8v*)&As[(wm + m * 16 + lr) * BK + lk];
#pragma unroll
        for (int n = 0; n < 4; n++) bf[n] = *(const short8v*)&Bs[(wn + n * 16 + lr) * BK + lk];
        __syncthreads();  // all waves done reading LDS
        if (k0 + BK < INDIM) {
            const int k1 = k0 + BK;
#pragma unroll
            for (int i = 0; i < 2; i++) {
                GLOAD_LDS16(A + (long)(bm + i * 64 + srow) * INDIM + k1 + scol, &As[(i * 64 + (w << 4)) * BK]);
                GLOAD_LDS16(Bw + (long)(bn + i * 64 + srow) * INDIM + k1 + scol, &Bs[(i * 64 + (w << 4)) * BK]);
            }
        }
#pragma unroll
        for (int m = 0; m < 4; m++)
#pragma unroll
            for (int n = 0; n < 4; n++)
                acc[m][n] = __builtin_amdgcn_mfma_f32_16x16x32_bf16(af[m], bf[n], acc[m][n], 0, 0, 0);
    }

    // epilogue: add bias, store fp32
#pragma unroll
    for (int m = 0; m < 4; m++) {
        const int row = bm + wm + m * 16 + (l >> 4) * 4;
#pragma unroll
        for (int n = 0; n < 4; n++) {
            const int col = bn + wn + n * 16 + lr;
            const float bv = bias[col];
#pragma unroll
            for (int r = 0; r < 4; r++)
                C[(long)(row + r) * NCOLS + col] = acc[m][n][r] + bv;
        }
    }
}

// ---------------- recurrence: 8 blocks = 4 batch-groups x 2 directions ----------------
// Swapped-operand MFMA: gates^T = Whh * h^T  => each lane holds i,f,g,o for
// (batch = lane&15, hidden cols = w*16 + (lane>>4)*4 + r) fully in registers.
// No gates LDS, one barrier per step, h double-buffered in LDS as bf16,
// xp prefetched ~2 steps ahead into registers.
__global__ __launch_bounds__(512, 2) void lstm_rec_kernel(const float* __restrict__ xp,
                                                          const float* __restrict__ Whh_f,
                                                          const float* __restrict__ Whh_b,
                                                          float* __restrict__ pooled) {
    __shared__ __align__(16) short hbf[2][16][136];  // [buf][batch][hidcol], stride 136

    const int bid = blockIdx.x;  // 0..7
    const int d = bid & 1;
    const int b0 = (bid >> 1) * 16;
    const int tid = threadIdx.x;
    const int w = tid >> 6;      // wave 0..7: owns hidden cols [16w, 16w+16)
    const int l = tid & 63;
    const int lr = l & 15;       // batch row (output col) / fragment row
    const int lg = l >> 4;       // 0..3
    const int lk = lg * 8;

    const float* __restrict__ Whh = d ? Whh_b : Whh_f;

    // Preload Whh as MFMA A-fragments (time-invariant):
    // afragW[nt][kk] = bf16(Whh[nt*128 + w*16 + lr][kk*32 + lk .. +8])
    short8v afragW[4][4];
#pragma unroll
    for (int nt = 0; nt < 4; nt++) {
        const int gc = nt * 128 + w * 16 + lr;
#pragma unroll
        for (int kk = 0; kk < 4; kk++) {
            const float* src = Whh + gc * HDIM + kk * 32 + lk;
            short8v f;
#pragma unroll
            for (int j = 0; j < 8; j++) f[j] = f2bf(src[j]);
            afragW[nt][kk] = f;
        }
    }

    // zero h buffer 0 (t=0 reads it)
    for (int i = tid; i < 16 * 136; i += 512) ((short*)hbf)[i] = 0;

    // per-lane xp base: row = batch b0+lr, cols d*512 + nt*128 + w*16 + lg*4 + [0,4)
    const float* xbase = xp + (long)(b0 + lr) * T_LEN * NCOLS + d * G4 + w * 16 + lg * 4;

    float c[4] = {0.f, 0.f, 0.f, 0.f};
    float hmax[4] = {-1e30f, -1e30f, -1e30f, -1e30f};

#define LOADXV(tq, dst) { \
    int tt_ = d ? (T_LEN - 1 - (tq)) : (tq); \
    tt_ = tt_ < 0 ? 0 : (tt_ > T_LEN - 1 ? T_LEN - 1 : tt_); \
    const float* p_ = xbase + (long)tt_ * NCOLS; \
    _Pragma("unroll") for (int nt_ = 0; nt_ < 4; nt_++) \
        dst[nt_] = *(const f32x4v*)(p_ + nt_ * 128); \
}

    f32x4v xvA[4], xvB[4];
    LOADXV(0, xvA);
    LOADXV(1, xvB);

    __syncthreads();

#define STEP(t, pb, xv) { \
    short8v hfrag[4]; \
    _Pragma("unroll") for (int kk = 0; kk < 4; kk++) \
        hfrag[kk] = *(const short8v*)&hbf[pb][lr][kk * 32 + lk]; \
    f32x4v acc[4]; \
    _Pragma("unroll") for (int nt = 0; nt < 4; nt++) { \
        acc[nt] = (f32x4v)0.0f; \
        _Pragma("unroll") for (int kk = 0; kk < 4; kk++) \
            acc[nt] = __builtin_amdgcn_mfma_f32_16x16x32_bf16(afragW[nt][kk], hfrag[kk], acc[nt], 0, 0, 0); \
    } \
    short4v ho; \
    _Pragma("unroll") for (int r = 0; r < 4; r++) { \
        float gi = acc[0][r] + xv[0][r]; \
        float gf = acc[1][r] + xv[1][r]; \
        float gg = acc[2][r] + xv[2][r]; \
        float go = acc[3][r] + xv[3][r]; \
        float si = 1.0f / (1.0f + __expf(-gi)); \
        float sf = 1.0f / (1.0f + __expf(-gf)); \
        float tg = 1.0f - 2.0f / (1.0f + __expf(2.0f * gg)); \
        float so = 1.0f / (1.0f + __expf(-go)); \
        c[r] = sf * c[r] + si * tg; \
        float tc = 1.0f - 2.0f / (1.0f + __expf(2.0f * c[r])); \
        float h = so * tc; \
        hmax[r] = fmaxf(hmax[r], h); \
        ho[r] = f2bf(h); \
    } \
    *(short4v*)&hbf[(pb) ^ 1][lr][w * 16 + lg * 4] = ho; \
    LOADXV((t) + 2, xv); \
    __syncthreads(); \
}

    for (int t = 0; t < T_LEN; t += 2) {
        STEP(t, 0, xvA);
        STEP(t + 1, 1, xvB);
    }

#pragma unroll
    for (int r = 0; r < 4; r++)
        pooled[(b0 + lr) * 256 + d * 128 + w * 16 + lg * 4 + r] = hmax[r];
#undef STEP
#undef LOADXV
}

// ---------------- head: out[64][263] = pooled[64][256] @ W1^T + b1 ----------------
__global__ void logits_kernel(const float* __restrict__ pooled, const float* __restrict__ W1,
                              const float* __restrict__ b1, float* __restrict__ out) {
    __shared__ float p[256];
    const int b = blockIdx.x;
    const int n = threadIdx.x;
    if (n < 256) p[n] = pooled[b * 256 + n];
    __syncthreads();
    if (n < NCLS) {
        float s = b1[n];
        const float* wr = W1 + n * 256;
#pragma unroll 8
        for (int k = 0; k < 256; k++) s += p[k] * wr[k];
        out[b * NCLS + n] = s;
    }
}

extern "C" void kernel_launch(void* const* d_in, const int* in_sizes, int n_in,
                              void* d_out, int out_size, void* d_ws, size_t ws_size,
                              hipStream_t stream) {
    (void)in_sizes; (void)n_in; (void)out_size; (void)ws_size;
    const float* x     = (const float*)d_in[0];
    const float* Wih_f = (const float*)d_in[1];
    const float* Whh_f = (const float*)d_in[2];
    const float* bih_f = (const float*)d_in[3];
    const float* bhh_f = (const float*)d_in[4];
    const float* Wih_b = (const float*)d_in[5];
    const float* Whh_b = (const float*)d_in[6];
    const float* bih_b = (const float*)d_in[7];
    const float* bhh_b = (const float*)d_in[8];
    const float* W1    = (const float*)d_in[9];
    const float* b1    = (const float*)d_in[10];
    float* out = (float*)d_out;

    char* ws = (char*)d_ws;
    short* x_bf   = (short*)ws;                    // 32768*1280*2  = 83,886,080
    short* w_bf   = (short*)(ws + 83886080);       // 1024*1280*2   =  2,621,440
    float* biasc  = (float*)(ws + 86507520);       // 1024*4        =      4,096
    float* xp     = (float*)(ws + 86511616);       // 32768*1024*4  = 134,217,728
    float* pooled = (float*)(ws + 220729344);      // 64*256*4      =     65,536

    convert_x_kernel<<<2048, 256, 0, stream>>>((const float4*)x, (short4v*)x_bf, (T_LEN * BATCH * INDIM) / 4);
    convert_w_kernel<<<512, 256, 0, stream>>>(Wih_f, Wih_b, bih_f, bhh_f, bih_b, bhh_b, w_bf, biasc);
    dim3 g(BATCH * T_LEN / BM, NCOLS / BN);  // (256, 8)
    gemm_xp_kernel<<<g, 256, 0, stream>>>(x_bf, w_bf, biasc, xp);
    lstm_rec_kernel<<<8, 512, 0, stream>>>(xp, Whh_f, Whh_b, pooled);
    logits_kernel<<<64, 320, 0, stream>>>(pooled, W1, b1, out);
}

// Round 3
// 728.462 us; speedup vs baseline: 1.5846x; 1.2892x over previous
//
#include <hip/hip_runtime.h>
#include <hip/hip_bf16.h>

typedef short short8v __attribute__((ext_vector_type(8)));
typedef short short4v __attribute__((ext_vector_type(4)));
typedef float f32x4v __attribute__((ext_vector_type(4)));

#define T_LEN 512
#define BATCH 64
#define INDIM 1280
#define HDIM 128
#define G4 512      // 4*H (one direction)
#define NCOLS 1024  // both directions
#define NCLS 263

typedef __attribute__((address_space(1))) const void gvoid_t;
typedef __attribute__((address_space(3))) void lvoid_t;
#define GLOAD_LDS16(g, l) __builtin_amdgcn_global_load_lds((gvoid_t*)(g), (lvoid_t*)(l), 16, 0, 0)

static __device__ __forceinline__ short f2bf(float f) {
    union { float f; unsigned u; } v; v.f = f;
    unsigned r = v.u + 0x7FFF + ((v.u >> 16) & 1);
    return (short)(r >> 16);
}

// ---------------- convert x (fp32) -> bf16 ----------------
__global__ void convert_x_kernel(const float4* __restrict__ x, short4v* __restrict__ out, int n4) {
    int i = blockIdx.x * blockDim.x + threadIdx.x;
    int stride = gridDim.x * blockDim.x;
    for (; i < n4; i += stride) {
        float4 v = x[i];
        short4v o;
        o[0] = f2bf(v.x); o[1] = f2bf(v.y); o[2] = f2bf(v.z); o[3] = f2bf(v.w);
        out[i] = o;
    }
}

// ---------------- convert Wih_f/Wih_b -> bf16 [1024][1280], combine biases ----------------
__global__ void convert_w_kernel(const float* __restrict__ Wf, const float* __restrict__ Wb,
                                 const float* __restrict__ bihf, const float* __restrict__ bhhf,
                                 const float* __restrict__ bihb, const float* __restrict__ bhhb,
                                 short* __restrict__ wout, float* __restrict__ biasc) {
    int i = blockIdx.x * blockDim.x + threadIdx.x;
    int stride = gridDim.x * blockDim.x;
    const int n4 = (G4 * INDIM) / 4;  // 163840 float4 per direction
    for (int k = i; k < 2 * n4; k += stride) {
        const float4* src = (k < n4) ? (const float4*)Wf : (const float4*)Wb;
        float4 v = src[(k < n4) ? k : (k - n4)];
        short4v o;
        o[0] = f2bf(v.x); o[1] = f2bf(v.y); o[2] = f2bf(v.z); o[3] = f2bf(v.w);
        ((short4v*)wout)[k] = o;
    }
    if (i < NCOLS)
        biasc[i] = (i < G4) ? (bihf[i] + bhhf[i]) : (bihb[i - G4] + bhhb[i - G4]);
}

// ---------------- big GEMM: xp[M=32768][1024] = x_bf16[M][1280] * w_bf16[1024][1280]^T + bias ----------------
#define BM 128
#define BN 128
#define BK 32

__global__ __launch_bounds__(256) void gemm_xp_kernel(const short* __restrict__ A,
                                                      const short* __restrict__ Bw,
                                                      const float* __restrict__ bias,
                                                      float* __restrict__ C) {
    __shared__ __align__(16) short As[BM * BK];
    __shared__ __align__(16) short Bs[BN * BK];
    const int tid = threadIdx.x;
    const int w = tid >> 6;
    const int l = tid & 63;
    const int bm = blockIdx.x * BM;
    const int bn = blockIdx.y * BN;
    const int wm = (w >> 1) * 64;
    const int wn = (w & 1) * 64;
    const int lr = l & 15;
    const int lk = (l >> 4) * 8;

    f32x4v acc[4][4];
#pragma unroll
    for (int m = 0; m < 4; m++)
#pragma unroll
        for (int n = 0; n < 4; n++) acc[m][n] = (f32x4v)0.0f;

    const int srow = tid >> 2;        // 0..63
    const int scol = (tid & 3) * 8;   // bf16 k-offset

    // prologue: stage tile k0=0
#pragma unroll
    for (int i = 0; i < 2; i++) {
        GLOAD_LDS16(A + (long)(bm + i * 64 + srow) * INDIM + scol, &As[(i * 64 + (w << 4)) * BK]);
        GLOAD_LDS16(Bw + (long)(bn + i * 64 + srow) * INDIM + scol, &Bs[(i * 64 + (w << 4)) * BK]);
    }

    for (int k0 = 0; k0 < INDIM; k0 += BK) {
        __syncthreads();  // staged data visible
        short8v af[4], bf[4];
#pragma unroll
        for (int m = 0; m < 4; m++) af[m] = *(const short8v*)&As[(wm + m * 16 + lr) * BK + lk];
#pragma unroll
        for (int n = 0; n < 4; n++) bf[n] = *(const short8v*)&Bs[(wn + n * 16 + lr) * BK + lk];
        __syncthreads();  // all waves done reading LDS
        if (k0 + BK < INDIM) {
            const int k1 = k0 + BK;
#pragma unroll
            for (int i = 0; i < 2; i++) {
                GLOAD_LDS16(A + (long)(bm + i * 64 + srow) * INDIM + k1 + scol, &As[(i * 64 + (w << 4)) * BK]);
                GLOAD_LDS16(Bw + (long)(bn + i * 64 + srow) * INDIM + k1 + scol, &Bs[(i * 64 + (w << 4)) * BK]);
            }
        }
#pragma unroll
        for (int m = 0; m < 4; m++)
#pragma unroll
            for (int n = 0; n < 4; n++)
                acc[m][n] = __builtin_amdgcn_mfma_f32_16x16x32_bf16(af[m], bf[n], acc[m][n], 0, 0, 0);
    }

    // epilogue: add bias, store fp32
#pragma unroll
    for (int m = 0; m < 4; m++) {
        const int row = bm + wm + m * 16 + (l >> 4) * 4;
#pragma unroll
        for (int n = 0; n < 4; n++) {
            const int col = bn + wn + n * 16 + lr;
            const float bv = bias[col];
#pragma unroll
            for (int r = 0; r < 4; r++)
                C[(long)(row + r) * NCOLS + col] = acc[m][n][r] + bv;
        }
    }
}

// ---------------- recurrence: 8 blocks = 4 batch-groups x 2 directions ----------------
// Swapped-operand MFMA: gates^T = Whh * h^T  => each lane holds i,f,g,o for
// (batch = lane&15, hidden cols = w*16 + (lane>>4)*4 + r) fully in registers.
// Per-step barrier is lgkmcnt(0)+s_barrier ONLY (no vmcnt drain) so the xp
// prefetch stays in flight across steps. Nonlinearities via native exp2 +
// v_rcp with rcp shared across gate pairs: 5 exp + 3 rcp per element.
__global__ __launch_bounds__(512, 2) void lstm_rec_kernel(const float* __restrict__ xp,
                                                          const float* __restrict__ Whh_f,
                                                          const float* __restrict__ Whh_b,
                                                          float* __restrict__ pooled) {
    __shared__ __align__(16) short hbf[2][16][136];  // [buf][batch][hidcol], stride 136

    const int bid = blockIdx.x;  // 0..7
    const int d = bid & 1;
    const int b0 = (bid >> 1) * 16;
    const int tid = threadIdx.x;
    const int w = tid >> 6;      // wave 0..7: owns hidden cols [16w, 16w+16)
    const int l = tid & 63;
    const int lr = l & 15;       // batch row (output col) / fragment row
    const int lg = l >> 4;       // 0..3
    const int lk = lg * 8;

    const float* __restrict__ Whh = d ? Whh_b : Whh_f;

    // Preload Whh as MFMA A-fragments (time-invariant):
    short8v afragW[4][4];
#pragma unroll
    for (int nt = 0; nt < 4; nt++) {
        const int gc = nt * 128 + w * 16 + lr;
#pragma unroll
        for (int kk = 0; kk < 4; kk++) {
            const float* src = Whh + gc * HDIM + kk * 32 + lk;
            short8v f;
#pragma unroll
            for (int j = 0; j < 8; j++) f[j] = f2bf(src[j]);
            afragW[nt][kk] = f;
        }
    }

    // zero h buffer 0 (t=0 reads it)
    for (int i = tid; i < 16 * 136; i += 512) ((short*)hbf)[i] = 0;

    // per-lane xp base: row = batch b0+lr, cols d*512 + nt*128 + w*16 + lg*4 + [0,4)
    const float* xbase = xp + (long)(b0 + lr) * T_LEN * NCOLS + d * G4 + w * 16 + lg * 4;

    float c[4] = {0.f, 0.f, 0.f, 0.f};
    float hmax[4] = {-1e30f, -1e30f, -1e30f, -1e30f};

#define LOADXV(tq, dst) { \
    int tt_ = d ? (T_LEN - 1 - (tq)) : (tq); \
    tt_ = tt_ < 0 ? 0 : (tt_ > T_LEN - 1 ? T_LEN - 1 : tt_); \
    const float* p_ = xbase + (long)tt_ * NCOLS; \
    _Pragma("unroll") for (int nt_ = 0; nt_ < 4; nt_++) \
        dst[nt_] = *(const f32x4v*)(p_ + nt_ * 128); \
}

    f32x4v xvA[4], xvB[4];
    LOADXV(0, xvA);
    LOADXV(1, xvB);

    __syncthreads();

#define L2E 1.44269504088896f

#define STEP(t, pb, xv) { \
    short8v hfrag[4]; \
    _Pragma("unroll") for (int kk = 0; kk < 4; kk++) \
        hfrag[kk] = *(const short8v*)&hbf[pb][lr][kk * 32 + lk]; \
    f32x4v acc[4]; \
    _Pragma("unroll") for (int nt = 0; nt < 4; nt++) { \
        acc[nt] = (f32x4v)0.0f; \
        _Pragma("unroll") for (int kk = 0; kk < 4; kk++) \
            acc[nt] = __builtin_amdgcn_mfma_f32_16x16x32_bf16(afragW[nt][kk], hfrag[kk], acc[nt], 0, 0, 0); \
    } \
    short4v ho; \
    _Pragma("unroll") for (int r = 0; r < 4; r++) { \
        float gi = acc[0][r] + xv[0][r]; \
        float gf = acc[1][r] + xv[1][r]; \
        float gg = acc[2][r] + xv[2][r]; \
        float go = acc[3][r] + xv[3][r]; \
        float ea = __builtin_amdgcn_exp2f(-gi * L2E); \
        float eb = __builtin_amdgcn_exp2f(-gf * L2E); \
        float pa = 1.0f + ea, pbv = 1.0f + eb; \
        float inv1 = __builtin_amdgcn_rcpf(pa * pbv); \
        float si = pbv * inv1; \
        float sf = pa * inv1; \
        float eg = __builtin_amdgcn_exp2f(gg * (2.0f * L2E)); \
        float eo = __builtin_amdgcn_exp2f(-go * L2E); \
        float pg = 1.0f + eg, po = 1.0f + eo; \
        float inv2 = __builtin_amdgcn_rcpf(pg * po); \
        float tg = 1.0f - 2.0f * po * inv2; \
        float so = pg * inv2; \
        c[r] = sf * c[r] + si * tg; \
        float ec = __builtin_amdgcn_exp2f(c[r] * (2.0f * L2E)); \
        float tc = 1.0f - 2.0f * __builtin_amdgcn_rcpf(1.0f + ec); \
        float h = so * tc; \
        hmax[r] = fmaxf(hmax[r], h); \
        ho[r] = f2bf(h); \
    } \
    *(short4v*)&hbf[(pb) ^ 1][lr][w * 16 + lg * 4] = ho; \
    LOADXV((t) + 2, xv); \
    asm volatile("s_waitcnt lgkmcnt(0)\n\ts_barrier" ::: "memory"); \
}

    for (int t = 0; t < T_LEN; t += 2) {
        STEP(t, 0, xvA);
        STEP(t + 1, 1, xvB);
    }

#pragma unroll
    for (int r = 0; r < 4; r++)
        pooled[(b0 + lr) * 256 + d * 128 + w * 16 + lg * 4 + r] = hmax[r];
#undef STEP
#undef LOADXV
}

// ---------------- head: out[64][263] = pooled[64][256] @ W1^T + b1 ----------------
__global__ void logits_kernel(const float* __restrict__ pooled, const float* __restrict__ W1,
                              const float* __restrict__ b1, float* __restrict__ out) {
    __shared__ float p[256];
    const int b = blockIdx.x;
    const int n = threadIdx.x;
    if (n < 256) p[n] = pooled[b * 256 + n];
    __syncthreads();
    if (n < NCLS) {
        float s = b1[n];
        const float* wr = W1 + n * 256;
#pragma unroll 8
        for (int k = 0; k < 256; k++) s += p[k] * wr[k];
        out[b * NCLS + n] = s;
    }
}

extern "C" void kernel_launch(void* const* d_in, const int* in_sizes, int n_in,
                              void* d_out, int out_size, void* d_ws, size_t ws_size,
                              hipStream_t stream) {
    (void)in_sizes; (void)n_in; (void)out_size; (void)ws_size;
    const float* x     = (const float*)d_in[0];
    const float* Wih_f = (const float*)d_in[1];
    const float* Whh_f = (const float*)d_in[2];
    const float* bih_f = (const float*)d_in[3];
    const float* bhh_f = (const float*)d_in[4];
    const float* Wih_b = (const float*)d_in[5];
    const float* Whh_b = (const float*)d_in[6];
    const float* bih_b = (const float*)d_in[7];
    const float* bhh_b = (const float*)d_in[8];
    const float* W1    = (const float*)d_in[9];
    const float* b1    = (const float*)d_in[10];
    float* out = (float*)d_out;

    char* ws = (char*)d_ws;
    short* x_bf   = (short*)ws;                    // 32768*1280*2  = 83,886,080
    short* w_bf   = (short*)(ws + 83886080);       // 1024*1280*2   =  2,621,440
    float* biasc  = (float*)(ws + 86507520);       // 1024*4        =      4,096
    float* xp     = (float*)(ws + 86511616);       // 32768*1024*4  = 134,217,728
    float* pooled = (float*)(ws + 220729344);      // 64*256*4      =     65,536

    convert_x_kernel<<<2048, 256, 0, stream>>>((const float4*)x, (short4v*)x_bf, (T_LEN * BATCH * INDIM) / 4);
    convert_w_kernel<<<512, 256, 0, stream>>>(Wih_f, Wih_b, bih_f, bhh_f, bih_b, bhh_b, w_bf, biasc);
    dim3 g(BATCH * T_LEN / BM, NCOLS / BN);  // (256, 8)
    gemm_xp_kernel<<<g, 256, 0, stream>>>(x_bf, w_bf, biasc, xp);
    lstm_rec_kernel<<<8, 512, 0, stream>>>(xp, Whh_f, Whh_b, pooled);
    logits_kernel<<<64, 320, 0, stream>>>(pooled, W1, b1, out);
}

// Round 4
// 545.176 us; speedup vs baseline: 2.1173x; 1.3362x over previous
//
#include <hip/hip_runtime.h>
#include <hip/hip_bf16.h>

typedef short short8v __attribute__((ext_vector_type(8)));
typedef short short4v __attribute__((ext_vector_type(4)));
typedef float f32x4v __attribute__((ext_vector_type(4)));

#define T_LEN 512
#define BATCH 64
#define INDIM 1280
#define HDIM 128
#define G4 512      // 4*H (one direction)
#define NCOLS 1024  // both directions
#define NCLS 263

typedef __attribute__((address_space(1))) const void gvoid_t;
typedef __attribute__((address_space(3))) void lvoid_t;
#define GLOAD_LDS16(g, l) __builtin_amdgcn_global_load_lds((gvoid_t*)(g), (lvoid_t*)(l), 16, 0, 0)

static __device__ __forceinline__ short f2bf(float f) {
    union { float f; unsigned u; } v; v.f = f;
    unsigned r = v.u + 0x7FFF + ((v.u >> 16) & 1);
    return (short)(r >> 16);
}

// ---------------- convert x (fp32) -> bf16 ----------------
__global__ void convert_x_kernel(const float4* __restrict__ x, short4v* __restrict__ out, int n4) {
    int i = blockIdx.x * blockDim.x + threadIdx.x;
    int stride = gridDim.x * blockDim.x;
    for (; i < n4; i += stride) {
        float4 v = x[i];
        short4v o;
        o[0] = f2bf(v.x); o[1] = f2bf(v.y); o[2] = f2bf(v.z); o[3] = f2bf(v.w);
        out[i] = o;
    }
}

// ---------------- convert Wih_f/Wih_b -> bf16 [1024][1280], combine biases ----------------
__global__ void convert_w_kernel(const float* __restrict__ Wf, const float* __restrict__ Wb,
                                 const float* __restrict__ bihf, const float* __restrict__ bhhf,
                                 const float* __restrict__ bihb, const float* __restrict__ bhhb,
                                 short* __restrict__ wout, float* __restrict__ biasc) {
    int i = blockIdx.x * blockDim.x + threadIdx.x;
    int stride = gridDim.x * blockDim.x;
    const int n4 = (G4 * INDIM) / 4;  // 163840 float4 per direction
    for (int k = i; k < 2 * n4; k += stride) {
        const float4* src = (k < n4) ? (const float4*)Wf : (const float4*)Wb;
        float4 v = src[(k < n4) ? k : (k - n4)];
        short4v o;
        o[0] = f2bf(v.x); o[1] = f2bf(v.y); o[2] = f2bf(v.z); o[3] = f2bf(v.w);
        ((short4v*)wout)[k] = o;
    }
    if (i < NCOLS)
        biasc[i] = (i < G4) ? (bihf[i] + bhhf[i]) : (bihb[i - G4] + bhhb[i - G4]);
}

// ---------------- big GEMM: xp[M=32768][1024] = x_bf16[M][1280] * w_bf16[1024][1280]^T + bias ----------------
#define BM 128
#define BN 128
#define BK 32

__global__ __launch_bounds__(256) void gemm_xp_kernel(const short* __restrict__ A,
                                                      const short* __restrict__ Bw,
                                                      const float* __restrict__ bias,
                                                      float* __restrict__ C) {
    __shared__ __align__(16) short As[BM * BK];
    __shared__ __align__(16) short Bs[BN * BK];
    const int tid = threadIdx.x;
    const int w = tid >> 6;
    const int l = tid & 63;
    const int bm = blockIdx.x * BM;
    const int bn = blockIdx.y * BN;
    const int wm = (w >> 1) * 64;
    const int wn = (w & 1) * 64;
    const int lr = l & 15;
    const int lk = (l >> 4) * 8;

    f32x4v acc[4][4];
#pragma unroll
    for (int m = 0; m < 4; m++)
#pragma unroll
        for (int n = 0; n < 4; n++) acc[m][n] = (f32x4v)0.0f;

    const int srow = tid >> 2;        // 0..63
    const int scol = (tid & 3) * 8;   // bf16 k-offset

    // prologue: stage tile k0=0
#pragma unroll
    for (int i = 0; i < 2; i++) {
        GLOAD_LDS16(A + (long)(bm + i * 64 + srow) * INDIM + scol, &As[(i * 64 + (w << 4)) * BK]);
        GLOAD_LDS16(Bw + (long)(bn + i * 64 + srow) * INDIM + scol, &Bs[(i * 64 + (w << 4)) * BK]);
    }

    for (int k0 = 0; k0 < INDIM; k0 += BK) {
        __syncthreads();  // staged data visible
        short8v af[4], bf[4];
#pragma unroll
        for (int m = 0; m < 4; m++) af[m] = *(const short8v*)&As[(wm + m * 16 + lr) * BK + lk];
#pragma unroll
        for (int n = 0; n < 4; n++) bf[n] = *(const short8v*)&Bs[(wn + n * 16 + lr) * BK + lk];
        __syncthreads();  // all waves done reading LDS
        if (k0 + BK < INDIM) {
            const int k1 = k0 + BK;
#pragma unroll
            for (int i = 0; i < 2; i++) {
                GLOAD_LDS16(A + (long)(bm + i * 64 + srow) * INDIM + k1 + scol, &As[(i * 64 + (w << 4)) * BK]);
                GLOAD_LDS16(Bw + (long)(bn + i * 64 + srow) * INDIM + k1 + scol, &Bs[(i * 64 + (w << 4)) * BK]);
            }
        }
#pragma unroll
        for (int m = 0; m < 4; m++)
#pragma unroll
            for (int n = 0; n < 4; n++)
                acc[m][n] = __builtin_amdgcn_mfma_f32_16x16x32_bf16(af[m], bf[n], acc[m][n], 0, 0, 0);
    }

    // epilogue: add bias, store fp32
#pragma unroll
    for (int m = 0; m < 4; m++) {
        const int row = bm + wm + m * 16 + (l >> 4) * 4;
#pragma unroll
        for (int n = 0; n < 4; n++) {
            const int col = bn + wn + n * 16 + lr;
            const float bv = bias[col];
#pragma unroll
            for (int r = 0; r < 4; r++)
                C[(long)(row + r) * NCOLS + col] = acc[m][n][r] + bv;
        }
    }
}

// ---------------- recurrence: 32 blocks = 16 batch-groups (4 batches) x 2 directions ----------------
// MFMA (swapped: gates^T = Whh * h^T) produces gates on 16 lanes (batch cols 0..3
// valid); gates are redistributed through an 8KB SoA LDS buffer glds[gate][batch][col]
// so that EVERY lane owns exactly ONE state element for the nonlinearity phase.
// Two lgkm-only barriers per step (no vmcnt drain); xp prefetched 2 steps ahead.
__global__ __launch_bounds__(512, 2) void lstm_rec_kernel(const float* __restrict__ xp,
                                                          const float* __restrict__ Whh_f,
                                                          const float* __restrict__ Whh_b,
                                                          float* __restrict__ pooled) {
    __shared__ __align__(16) short hbf[2][16][136];   // h bf16, rows 4..15 stay zero
    __shared__ __align__(16) float glds[4][4][128];   // [gate i,f,g,o][batch][col]

    const int bid = blockIdx.x;  // 0..31
    const int d = bid & 1;
    const int b0 = (bid >> 1) * 4;   // 4 batches per block
    const int tid = threadIdx.x;
    const int w = tid >> 6;      // wave 0..7: owns hidden cols [16w, 16w+16)
    const int l = tid & 63;
    const int lr = l & 15;       // MFMA: batch col
    const int lg = l >> 4;       // 0..3
    const int lk = lg * 8;

    const float* __restrict__ Whh = d ? Whh_b : Whh_f;

    // Preload Whh as MFMA A-fragments (time-invariant):
    // afragW[nt][kk] = bf16(Whh[nt*128 + w*16 + lr][kk*32 + lk .. +8])
    short8v afragW[4][4];
#pragma unroll
    for (int nt = 0; nt < 4; nt++) {
        const int gc = nt * 128 + w * 16 + lr;
#pragma unroll
        for (int kk = 0; kk < 4; kk++) {
            const float* src = Whh + gc * HDIM + kk * 32 + lk;
            short8v f;
#pragma unroll
            for (int j = 0; j < 8; j++) f[j] = f2bf(src[j]);
            afragW[nt][kk] = f;
        }
    }

    // zero both h buffers (fake batch rows 4..15 must be zero forever)
    for (int i = tid; i < 2 * 16 * 136; i += 512) ((short*)hbf)[i] = 0;

    // elementwise ownership: one element per lane
    const int eb = tid >> 7;     // batch 0..3
    const int ec = tid & 127;    // hidden col 0..127
    const float* xbase = xp + (long)(b0 + eb) * T_LEN * NCOLS + d * G4 + ec;

    float c = 0.0f;
    float hmax = -1e30f;

#define LOADXV(tq, dst) { \
    int tt_ = d ? (T_LEN - 1 - (tq)) : (tq); \
    tt_ = tt_ < 0 ? 0 : (tt_ > T_LEN - 1 ? T_LEN - 1 : tt_); \
    const float* p_ = xbase + (long)tt_ * NCOLS; \
    _Pragma("unroll") for (int nt_ = 0; nt_ < 4; nt_++) \
        dst[nt_] = p_[nt_ * 128]; \
}

    float xvA[4], xvB[4];
    LOADXV(0, xvA);
    LOADXV(1, xvB);

    __syncthreads();

#define L2E 1.44269504088896f

#define STEP(t, pb, xv) { \
    short8v hfrag[4]; \
    _Pragma("unroll") for (int kk = 0; kk < 4; kk++) \
        hfrag[kk] = *(const short8v*)&hbf[pb][lr][kk * 32 + lk]; \
    f32x4v acc[4]; \
    _Pragma("unroll") for (int nt = 0; nt < 4; nt++) { \
        acc[nt] = (f32x4v)0.0f; \
        _Pragma("unroll") for (int kk = 0; kk < 4; kk++) \
            acc[nt] = __builtin_amdgcn_mfma_f32_16x16x32_bf16(afragW[nt][kk], hfrag[kk], acc[nt], 0, 0, 0); \
    } \
    if (lr < 4) { \
        _Pragma("unroll") for (int nt = 0; nt < 4; nt++) \
            *(f32x4v*)&glds[nt][lr][w * 16 + lg * 4] = acc[nt]; \
    } \
    asm volatile("s_waitcnt lgkmcnt(0)\n\ts_barrier" ::: "memory"); \
    { \
        float gi = glds[0][eb][ec] + xv[0]; \
        float gf = glds[1][eb][ec] + xv[1]; \
        float gg = glds[2][eb][ec] + xv[2]; \
        float go = glds[3][eb][ec] + xv[3]; \
        float ea = __builtin_amdgcn_exp2f(-gi * L2E); \
        float eb_ = __builtin_amdgcn_exp2f(-gf * L2E); \
        float pa = 1.0f + ea, pbv = 1.0f + eb_; \
        float inv1 = __builtin_amdgcn_rcpf(pa * pbv); \
        float si = pbv * inv1; \
        float sf = pa * inv1; \
        float eg = __builtin_amdgcn_exp2f(gg * (2.0f * L2E)); \
        float eo = __builtin_amdgcn_exp2f(-go * L2E); \
        float pg = 1.0f + eg, po = 1.0f + eo; \
        float inv2 = __builtin_amdgcn_rcpf(pg * po); \
        float tg = 1.0f - 2.0f * po * inv2; \
        float so = pg * inv2; \
        c = sf * c + si * tg; \
        float ecx = __builtin_amdgcn_exp2f(c * (2.0f * L2E)); \
        float tc = 1.0f - 2.0f * __builtin_amdgcn_rcpf(1.0f + ecx); \
        float h = so * tc; \
        hmax = fmaxf(hmax, h); \
        hbf[(pb) ^ 1][eb][ec] = f2bf(h); \
    } \
    LOADXV((t) + 2, xv); \
    asm volatile("s_waitcnt lgkmcnt(0)\n\ts_barrier" ::: "memory"); \
}

    for (int t = 0; t < T_LEN; t += 2) {
        STEP(t, 0, xvA);
        STEP(t + 1, 1, xvB);
    }

    pooled[(b0 + eb) * 256 + d * 128 + ec] = hmax;
#undef STEP
#undef LOADXV
}

// ---------------- head: out[64][263] = pooled[64][256] @ W1^T + b1 ----------------
__global__ void logits_kernel(const float* __restrict__ pooled, const float* __restrict__ W1,
                              const float* __restrict__ b1, float* __restrict__ out) {
    __shared__ float p[256];
    const int b = blockIdx.x;
    const int n = threadIdx.x;
    if (n < 256) p[n] = pooled[b * 256 + n];
    __syncthreads();
    if (n < NCLS) {
        float s = b1[n];
        const float* wr = W1 + n * 256;
#pragma unroll 8
        for (int k = 0; k < 256; k++) s += p[k] * wr[k];
        out[b * NCLS + n] = s;
    }
}

extern "C" void kernel_launch(void* const* d_in, const int* in_sizes, int n_in,
                              void* d_out, int out_size, void* d_ws, size_t ws_size,
                              hipStream_t stream) {
    (void)in_sizes; (void)n_in; (void)out_size; (void)ws_size;
    const float* x     = (const float*)d_in[0];
    const float* Wih_f = (const float*)d_in[1];
    const float* Whh_f = (const float*)d_in[2];
    const float* bih_f = (const float*)d_in[3];
    const float* bhh_f = (const float*)d_in[4];
    const float* Wih_b = (const float*)d_in[5];
    const float* Whh_b = (const float*)d_in[6];
    const float* bih_b = (const float*)d_in[7];
    const float* bhh_b = (const float*)d_in[8];
    const float* W1    = (const float*)d_in[9];
    const float* b1    = (const float*)d_in[10];
    float* out = (float*)d_out;

    char* ws = (char*)d_ws;
    short* x_bf   = (short*)ws;                    // 32768*1280*2  = 83,886,080
    short* w_bf   = (short*)(ws + 83886080);       // 1024*1280*2   =  2,621,440
    float* biasc  = (float*)(ws + 86507520);       // 1024*4        =      4,096
    float* xp     = (float*)(ws + 86511616);       // 32768*1024*4  = 134,217,728
    float* pooled = (float*)(ws + 220729344);      // 64*256*4      =     65,536

    convert_x_kernel<<<2048, 256, 0, stream>>>((const float4*)x, (short4v*)x_bf, (T_LEN * BATCH * INDIM) / 4);
    convert_w_kernel<<<512, 256, 0, stream>>>(Wih_f, Wih_b, bih_f, bhh_f, bih_b, bhh_b, w_bf, biasc);
    dim3 g(BATCH * T_LEN / BM, NCOLS / BN);  // (256, 8)
    gemm_xp_kernel<<<g, 256, 0, stream>>>(x_bf, w_bf, biasc, xp);
    lstm_rec_kernel<<<32, 512, 0, stream>>>(xp, Whh_f, Whh_b, pooled);
    logits_kernel<<<64, 320, 0, stream>>>(pooled, W1, b1, out);
}

// Round 5
// 504.557 us; speedup vs baseline: 2.2877x; 1.0805x over previous
//
#include <hip/hip_runtime.h>
#include <hip/hip_bf16.h>

typedef short short8v __attribute__((ext_vector_type(8)));
typedef short short4v __attribute__((ext_vector_type(4)));
typedef float f32x4v __attribute__((ext_vector_type(4)));

#define T_LEN 512
#define BATCH 64
#define INDIM 1280
#define HDIM 128
#define G4 512      // 4*H (one direction)
#define NCOLS 1024  // both directions
#define NCLS 263

typedef __attribute__((address_space(1))) const void gvoid_t;
typedef __attribute__((address_space(3))) void lvoid_t;
#define GLOAD_LDS16(g, l) __builtin_amdgcn_global_load_lds((gvoid_t*)(g), (lvoid_t*)(l), 16, 0, 0)

static __device__ __forceinline__ short f2bf(float f) {
    union { float f; unsigned u; } v; v.f = f;
    unsigned r = v.u + 0x7FFF + ((v.u >> 16) & 1);
    return (short)(r >> 16);
}

// ---------------- convert x (fp32) -> bf16 ----------------
__global__ void convert_x_kernel(const float4* __restrict__ x, short4v* __restrict__ out, int n4) {
    int i = blockIdx.x * blockDim.x + threadIdx.x;
    int stride = gridDim.x * blockDim.x;
    for (; i < n4; i += stride) {
        float4 v = x[i];
        short4v o;
        o[0] = f2bf(v.x); o[1] = f2bf(v.y); o[2] = f2bf(v.z); o[3] = f2bf(v.w);
        out[i] = o;
    }
}

// ---------------- convert Wih_f/Wih_b -> bf16 [1024][1280], combine biases ----------------
__global__ void convert_w_kernel(const float* __restrict__ Wf, const float* __restrict__ Wb,
                                 const float* __restrict__ bihf, const float* __restrict__ bhhf,
                                 const float* __restrict__ bihb, const float* __restrict__ bhhb,
                                 short* __restrict__ wout, float* __restrict__ biasc) {
    int i = blockIdx.x * blockDim.x + threadIdx.x;
    int stride = gridDim.x * blockDim.x;
    const int n4 = (G4 * INDIM) / 4;  // 163840 float4 per direction
    for (int k = i; k < 2 * n4; k += stride) {
        const float4* src = (k < n4) ? (const float4*)Wf : (const float4*)Wb;
        float4 v = src[(k < n4) ? k : (k - n4)];
        short4v o;
        o[0] = f2bf(v.x); o[1] = f2bf(v.y); o[2] = f2bf(v.z); o[3] = f2bf(v.w);
        ((short4v*)wout)[k] = o;
    }
    if (i < NCOLS)
        biasc[i] = (i < G4) ? (bihf[i] + bhhf[i]) : (bihb[i - G4] + bhhb[i - G4]);
}

// ---------------- big GEMM: xp[M=32768][1024] = x_bf16[M][1280] * w_bf16[1024][1280]^T + bias ----------------
#define BM 128
#define BN 128
#define BK 32

__global__ __launch_bounds__(256) void gemm_xp_kernel(const short* __restrict__ A,
                                                      const short* __restrict__ Bw,
                                                      const float* __restrict__ bias,
                                                      float* __restrict__ C) {
    __shared__ __align__(16) short As[BM * BK];
    __shared__ __align__(16) short Bs[BN * BK];
    const int tid = threadIdx.x;
    const int w = tid >> 6;
    const int l = tid & 63;
    const int bm = blockIdx.x * BM;
    const int bn = blockIdx.y * BN;
    const int wm = (w >> 1) * 64;
    const int wn = (w & 1) * 64;
    const int lr = l & 15;
    const int lk = (l >> 4) * 8;

    f32x4v acc[4][4];
#pragma unroll
    for (int m = 0; m < 4; m++)
#pragma unroll
        for (int n = 0; n < 4; n++) acc[m][n] = (f32x4v)0.0f;

    const int srow = tid >> 2;        // 0..63
    const int scol = (tid & 3) * 8;   // bf16 k-offset

    // prologue: stage tile k0=0
#pragma unroll
    for (int i = 0; i < 2; i++) {
        GLOAD_LDS16(A + (long)(bm + i * 64 + srow) * INDIM + scol, &As[(i * 64 + (w << 4)) * BK]);
        GLOAD_LDS16(Bw + (long)(bn + i * 64 + srow) * INDIM + scol, &Bs[(i * 64 + (w << 4)) * BK]);
    }

    for (int k0 = 0; k0 < INDIM; k0 += BK) {
        __syncthreads();  // staged data visible
        short8v af[4], bf[4];
#pragma unroll
        for (int m = 0; m < 4; m++) af[m] = *(const short8v*)&As[(wm + m * 16 + lr) * BK + lk];
#pragma unroll
        for (int n = 0; n < 4; n++) bf[n] = *(const short8v*)&Bs[(wn + n * 16 + lr) * BK + lk];
        __syncthreads();  // all waves done reading LDS
        if (k0 + BK < INDIM) {
            const int k1 = k0 + BK;
#pragma unroll
            for (int i = 0; i < 2; i++) {
                GLOAD_LDS16(A + (long)(bm + i * 64 + srow) * INDIM + k1 + scol, &As[(i * 64 + (w << 4)) * BK]);
                GLOAD_LDS16(Bw + (long)(bn + i * 64 + srow) * INDIM + k1 + scol, &Bs[(i * 64 + (w << 4)) * BK]);
            }
        }
#pragma unroll
        for (int m = 0; m < 4; m++)
#pragma unroll
            for (int n = 0; n < 4; n++)
                acc[m][n] = __builtin_amdgcn_mfma_f32_16x16x32_bf16(af[m], bf[n], acc[m][n], 0, 0, 0);
    }

    // epilogue: add bias, store fp32
#pragma unroll
    for (int m = 0; m < 4; m++) {
        const int row = bm + wm + m * 16 + (l >> 4) * 4;
#pragma unroll
        for (int n = 0; n < 4; n++) {
            const int col = bn + wn + n * 16 + lr;
            const float bv = bias[col];
#pragma unroll
            for (int r = 0; r < 4; r++)
                C[(long)(row + r) * NCOLS + col] = acc[m][n][r] + bv;
        }
    }
}

// ---------------- recurrence: 64 blocks = 32 batch-groups (2 batches) x 2 directions ----------------
// 256 threads = 4 waves (1/SIMD). Wave w owns gate w (rows [w*128,(w+1)*128) of Whh).
// Swapped MFMA: gates^T = Whh * h^T, batch on output cols (lr), only cols 0..1 valid.
// Gates redistributed via glds[4][2][136] (stride 136 => conflict-free b128 writes);
// h stored as hbf[buf][3][136] bf16 where row 2 is a shared zero row: fragment-read
// lanes with lr>=2 all hit the same address (broadcast, free).
// Two lgkm-only barriers per step (no vmcnt drain); xp prefetched 2 steps ahead.
__global__ __launch_bounds__(256, 1) void lstm_rec_kernel(const float* __restrict__ xp,
                                                          const float* __restrict__ Whh_f,
                                                          const float* __restrict__ Whh_b,
                                                          float* __restrict__ pooled) {
    __shared__ __align__(16) short hbf[2][3][136];    // rows 0,1 = batches; row 2 = zeros
    __shared__ __align__(16) float glds[4][2][136];   // [gate i,f,g,o][batch][col]

    const int bid = blockIdx.x;  // 0..63
    const int d = bid & 1;
    const int b0 = (bid >> 1) * 2;   // 2 batches per block
    const int tid = threadIdx.x;
    const int w = tid >> 6;      // wave 0..3 = gate index
    const int l = tid & 63;
    const int lr = l & 15;       // MFMA fragment row / output col (batch)
    const int lg = l >> 4;       // 0..3
    const int lk = lg * 8;
    const int hrow = lr < 2 ? lr : 2;  // broadcast zero row for invalid batches

    const float* __restrict__ Whh = d ? Whh_b : Whh_f;

    // Preload Whh as MFMA A-fragments (time-invariant), wave w -> gate w:
    // afragW[nt][kk] = bf16(Whh[w*128 + nt*16 + lr][kk*32 + lk .. +8])
    short8v afragW[8][4];
#pragma unroll
    for (int nt = 0; nt < 8; nt++) {
        const int gc = w * 128 + nt * 16 + lr;
#pragma unroll
        for (int kk = 0; kk < 4; kk++) {
            const float* src = Whh + gc * HDIM + kk * 32 + lk;
            short8v f;
#pragma unroll
            for (int j = 0; j < 8; j++) f[j] = f2bf(src[j]);
            afragW[nt][kk] = f;
        }
    }

    // zero both h buffers (row 2 must stay zero forever)
    for (int i = tid; i < 2 * 3 * 136; i += 256) ((short*)hbf)[i] = 0;

    // elementwise ownership: one element per lane
    const int eb = tid >> 7;     // batch 0..1
    const int ec = tid & 127;    // hidden col 0..127
    const float* xbase = xp + (long)(b0 + eb) * T_LEN * NCOLS + d * G4 + ec;

    float c = 0.0f;
    float hmax = -1e30f;

#define LOADXV(tq, dst) { \
    int tt_ = d ? (T_LEN - 1 - (tq)) : (tq); \
    tt_ = tt_ < 0 ? 0 : (tt_ > T_LEN - 1 ? T_LEN - 1 : tt_); \
    const float* p_ = xbase + (long)tt_ * NCOLS; \
    _Pragma("unroll") for (int nt_ = 0; nt_ < 4; nt_++) \
        dst[nt_] = p_[nt_ * 128]; \
}

    float xvA[4], xvB[4];
    LOADXV(0, xvA);
    LOADXV(1, xvB);

    __syncthreads();

#define L2E 1.44269504088896f

#define STEP(t, pb, xv) { \
    short8v hfrag[4]; \
    _Pragma("unroll") for (int kk = 0; kk < 4; kk++) \
        hfrag[kk] = *(const short8v*)&hbf[pb][hrow][kk * 32 + lk]; \
    _Pragma("unroll") for (int nt = 0; nt < 8; nt++) { \
        f32x4v a = (f32x4v)0.0f; \
        _Pragma("unroll") for (int kk = 0; kk < 4; kk++) \
            a = __builtin_amdgcn_mfma_f32_16x16x32_bf16(afragW[nt][kk], hfrag[kk], a, 0, 0, 0); \
        if (lr < 2) *(f32x4v*)&glds[w][lr][nt * 16 + lg * 4] = a; \
    } \
    asm volatile("s_waitcnt lgkmcnt(0)\n\ts_barrier" ::: "memory"); \
    { \
        float gi = glds[0][eb][ec] + xv[0]; \
        float gf = glds[1][eb][ec] + xv[1]; \
        float gg = glds[2][eb][ec] + xv[2]; \
        float go = glds[3][eb][ec] + xv[3]; \
        float ea = __builtin_amdgcn_exp2f(-gi * L2E); \
        float eb_ = __builtin_amdgcn_exp2f(-gf * L2E); \
        float pa = 1.0f + ea, pbv = 1.0f + eb_; \
        float inv1 = __builtin_amdgcn_rcpf(pa * pbv); \
        float si = pbv * inv1; \
        float sf = pa * inv1; \
        float eg = __builtin_amdgcn_exp2f(gg * (2.0f * L2E)); \
        float eo = __builtin_amdgcn_exp2f(-go * L2E); \
        float pg = 1.0f + eg, po = 1.0f + eo; \
        float inv2 = __builtin_amdgcn_rcpf(pg * po); \
        float tg = 1.0f - 2.0f * po * inv2; \
        float so = pg * inv2; \
        c = sf * c + si * tg; \
        float ecx = __builtin_amdgcn_exp2f(c * (2.0f * L2E)); \
        float tc = 1.0f - 2.0f * __builtin_amdgcn_rcpf(1.0f + ecx); \
        float h = so * tc; \
        hmax = fmaxf(hmax, h); \
        hbf[(pb) ^ 1][eb][ec] = f2bf(h); \
    } \
    LOADXV((t) + 2, xv); \
    asm volatile("s_waitcnt lgkmcnt(0)\n\ts_barrier" ::: "memory"); \
}

    for (int t = 0; t < T_LEN; t += 2) {
        STEP(t, 0, xvA);
        STEP(t + 1, 1, xvB);
    }

    pooled[(b0 + eb) * 256 + d * 128 + ec] = hmax;
#undef STEP
#undef LOADXV
}

// ---------------- head: out[64][263] = pooled[64][256] @ W1^T + b1 ----------------
__global__ void logits_kernel(const float* __restrict__ pooled, const float* __restrict__ W1,
                              const float* __restrict__ b1, float* __restrict__ out) {
    __shared__ float p[256];
    const int b = blockIdx.x;
    const int n = threadIdx.x;
    if (n < 256) p[n] = pooled[b * 256 + n];
    __syncthreads();
    if (n < NCLS) {
        float s = b1[n];
        const float* wr = W1 + n * 256;
#pragma unroll 8
        for (int k = 0; k < 256; k++) s += p[k] * wr[k];
        out[b * NCLS + n] = s;
    }
}

extern "C" void kernel_launch(void* const* d_in, const int* in_sizes, int n_in,
                              void* d_out, int out_size, void* d_ws, size_t ws_size,
                              hipStream_t stream) {
    (void)in_sizes; (void)n_in; (void)out_size; (void)ws_size;
    const float* x     = (const float*)d_in[0];
    const float* Wih_f = (const float*)d_in[1];
    const float* Whh_f = (const float*)d_in[2];
    const float* bih_f = (const float*)d_in[3];
    const float* bhh_f = (const float*)d_in[4];
    const float* Wih_b = (const float*)d_in[5];
    const float* Whh_b = (const float*)d_in[6];
    const float* bih_b = (const float*)d_in[7];
    const float* bhh_b = (const float*)d_in[8];
    const float* W1    = (const float*)d_in[9];
    const float* b1    = (const float*)d_in[10];
    float* out = (float*)d_out;

    char* ws = (char*)d_ws;
    short* x_bf   = (short*)ws;                    // 32768*1280*2  = 83,886,080
    short* w_bf   = (short*)(ws + 83886080);       // 1024*1280*2   =  2,621,440
    float* biasc  = (float*)(ws + 86507520);       // 1024*4        =      4,096
    float* xp     = (float*)(ws + 86511616);       // 32768*1024*4  = 134,217,728
    float* pooled = (float*)(ws + 220729344);      // 64*256*4      =     65,536

    convert_x_kernel<<<2048, 256, 0, stream>>>((const float4*)x, (short4v*)x_bf, (T_LEN * BATCH * INDIM) / 4);
    convert_w_kernel<<<512, 256, 0, stream>>>(Wih_f, Wih_b, bih_f, bhh_f, bih_b, bhh_b, w_bf, biasc);
    dim3 g(BATCH * T_LEN / BM, NCOLS / BN);  // (256, 8)
    gemm_xp_kernel<<<g, 256, 0, stream>>>(x_bf, w_bf, biasc, xp);
    lstm_rec_kernel<<<64, 256, 0, stream>>>(xp, Whh_f, Whh_b, pooled);
    logits_kernel<<<64, 320, 0, stream>>>(pooled, W1, b1, out);
}